// Round 6
// baseline (52213.330 us; speedup 1.0000x reference)
//
#include <hip/hip_runtime.h>
#include <stdint.h>

// Problem dims
#define B_    64
#define T_    2048
#define IN_   64
#define H_    512
#define H2_   1024
#define OUT_  32
#define KTOT  576          // IN_ + H_

// Grid: 256 blocks = 8 batch-groups x 32 col-groups, 256 threads.
#define NBG   8
#define NCG   32
#define NTHR  256
#define BPG   8            // batches per group
#define KSL   18           // k per slice (32 slices x 18 = 576)
#define RS    12           // bufA row stride in floats

// ws layout (32-bit words)
// Flag-vector barrier: slot(bg,ph,cg) = ((bg*2+ph)*NCG + cg) * FLAG_STRIDE.
// Each slot on its own 64B line; written (plain agent store) with value t+1,
// monotonically increasing -> one-shot semantics, no reset, no atomics.
#define FLAG_STRIDE 16
#define FLAG_WORDS  (NBG * 2 * NCG * FLAG_STRIDE)   // 8192
#define ABORT_IDX   FLAG_WORDS                       // 8192
#define BUF_BASE    (FLAG_WORDS + 16)                // 8208, 64B-aligned
#define XSLAB       32768    // words per slab: [8 bg][512 j][8 b]

__global__ __launch_bounds__(256) void gru_init(float* ws, const float* __restrict__ x0) {
  int i = blockIdx.x * blockDim.x + threadIdx.x;
  int stride = gridDim.x * blockDim.x;
  unsigned* w = (unsigned*)ws;
  for (int k = i; k < BUF_BASE; k += stride) w[k] = 0u;
  // xg0[bg][j][b] = x0[(bg*8+b)*512 + j]
  for (int k = i; k < NBG * H_ * BPG; k += stride) {
    int bg = k >> 12, j = (k >> 3) & (H_ - 1), b = k & 7;
    ws[BUF_BASE + k] = x0[(bg * 8 + b) * H_ + j];
  }
}

// arrive: all data written with PLAIN stores; __syncthreads drains vmcnt of
// every wave; one buffer_wbl2 (release-agent fence) flushes L2->MALL; then a
// single relaxed agent store publishes flag = t+1. No atomics.
__device__ __forceinline__ void gbar_arrive(unsigned* flags, int slot, unsigned target) {
  __syncthreads();
  if (threadIdx.x == 0) {
    __builtin_amdgcn_fence(__ATOMIC_RELEASE, "agent");
    __hip_atomic_store(flags + slot, target, __ATOMIC_RELAXED, __HIP_MEMORY_SCOPE_AGENT);
  }
}

// wait: 32 lanes of wave 0 poll 32 DISTINCT 64B-spaced slots in parallel
// (no line contention), ballot-combine, then block-wide acquire fence
// (buffer_inv) so subsequent plain vector loads see MALL-fresh data.
__device__ __forceinline__ bool gbar_wait(unsigned* flags, int base, unsigned target,
                                          unsigned* abort_w) {
  __shared__ int s_ok;
  const int tid = threadIdx.x;
  int ok = 1;
  if (tid < NCG) {
    const unsigned* f = flags + base + tid * FLAG_STRIDE;
    int polls = 0;
    while (__hip_atomic_load(f, __ATOMIC_RELAXED, __HIP_MEMORY_SCOPE_AGENT) < target) {
      __builtin_amdgcn_s_sleep(1);
      if ((++polls & 255) == 0) {
        if (__hip_atomic_load(abort_w, __ATOMIC_RELAXED, __HIP_MEMORY_SCOPE_AGENT) != 0u ||
            polls > 2000000) {
          __hip_atomic_store(abort_w, 1u, __ATOMIC_RELAXED, __HIP_MEMORY_SCOPE_AGENT);
          ok = 0;
          break;
        }
      }
    }
  }
  if (tid < 64) {
    unsigned long long bad = __ballot(ok == 0);
    if (tid == 0) s_ok = (bad == 0ull) ? 1 : 0;
  }
  __syncthreads();
  __builtin_amdgcn_fence(__ATOMIC_ACQUIRE, "agent");  // per-wave buffer_inv
  return s_ok != 0;
}

__global__ __launch_bounds__(NTHR, 1) void gru_main(
    const float* __restrict__ u, const float* __restrict__ kfz,
    const float* __restrict__ bfz, const float* __restrict__ kr,
    const float* __restrict__ br, const float* __restrict__ wout,
    const float* __restrict__ bout, float* __restrict__ out, float* ws) {
  unsigned* flags = (unsigned*)ws;
  unsigned* abort_w = flags + ABORT_IDX;
  float* xg0 = ws + BUF_BASE;
  float* xg1 = xg0 + XSLAB;
  float* xfg = xg1 + XSLAB;

  const int bg  = blockIdx.x & 7;
  const int cg  = blockIdx.x >> 3;   // column group 0..31
  const int tid = threadIdx.x;
  const int w   = tid >> 6;          // wave 0..3
  const int l   = tid & 63;
  const int cq  = l & 7;             // col-quad 0..7
  const int g   = l >> 3;            // in-wave k-slice 0..7
  const int kb  = (w * 8 + g) * KSL; // this thread's k base (18 k's)
  const int fc  = tid >> 3;          // finalize col 0..31
  const int fb  = tid & 7;           // finalize batch 0..7
  const int yb  = tid >> 5;          // y batch 0..7
  const int yq  = tid & 31;          // y k-slice 0..31

  const int slotA = ((bg * 2 + 0) * NCG + cg) * FLAG_STRIDE;
  const int slotB = ((bg * 2 + 1) * NCG + cg) * FLAG_STRIDE;
  const int baseA = (bg * 2 + 0) * NCG * FLAG_STRIDE;
  const int baseB = (bg * 2 + 1) * NCG * FLAG_STRIDE;

  __shared__ float bufA[KTOT * RS];  // [k][12]: u_t(k<64) | x or f*x
  __shared__ float pA[4 * 32 * RS];
  __shared__ float pB[4 * 16 * RS];
  __shared__ float rbuf[16 * 8];

  // ---- one-time: weights into registers ----
  float wA[KSL][4];
#pragma unroll
  for (int i = 0; i < KSL; ++i)
#pragma unroll
    for (int m = 0; m < 4; ++m) {
      int c = 4 * cq + m;
      int gcol = (c < 16) ? (16 * cg + c) : (512 + 16 * cg + (c - 16));
      wA[i][m] = kfz[(size_t)(kb + i) * H2_ + gcol];
    }
  float wB[KSL][2];
#pragma unroll
  for (int i = 0; i < KSL; ++i)
#pragma unroll
    for (int m = 0; m < 2; ++m)
      wB[i][m] = kr[(size_t)(kb + i) * H_ + (16 * cg + 2 * cq + m)];
  float wy[16];
#pragma unroll
  for (int i = 0; i < 16; ++i) wy[i] = wout[cg * H_ + (yq + 32 * i)];
  const float by = bout[cg];
  const int fzc = (fc < 16) ? (16 * cg + fc) : (512 + 16 * cg + (fc - 16));
  const float biasA = bfz[fzc];
  const float biasB = (tid < 128) ? br[16 * cg + fc] : 0.0f;

  float zreg = 0.0f, xoldz = 0.0f;

  // u_t=0 into LDS (later steps prefetched during barrier-2 window)
  {
    int k2 = tid & 31, b = tid >> 5;
    float2 uv = *(const float2*)&u[((size_t)(bg * 8 + b) * T_) * IN_ + 2 * k2];
    bufA[(2 * k2) * RS + b] = uv.x;
    bufA[(2 * k2 + 1) * RS + b] = uv.y;
  }

  for (int t = 0; t < T_; ++t) {
    float* xcur = (t & 1) ? xg1 : xg0;
    float* xnxt = (t & 1) ? xg0 : xg1;

    // ---- stage x into bufA (plain dwordx4; fresh after acquire fence) ----
    {
      const float* src = &xcur[(size_t)(bg * H_ + tid) * 8];
      float4 p0 = *(const float4*)src;
      float4 p1 = *(const float4*)(src + 4);
      *(float4*)&bufA[(64 + tid) * RS] = p0;
      *(float4*)&bufA[(64 + tid) * RS + 4] = p1;
      src = &xcur[(size_t)(bg * H_ + tid + 256) * 8];
      p0 = *(const float4*)src;
      p1 = *(const float4*)(src + 4);
      *(float4*)&bufA[(64 + tid + 256) * RS] = p0;
      *(float4*)&bufA[(64 + tid + 256) * RS + 4] = p1;
    }
    __syncthreads();

    // ---- phase A core: fz partials for 4 cols x 8 batches over 18 k ----
    float acc[4][8] = {};
#pragma unroll
    for (int i = 0; i < KSL; ++i) {
      const float* xr = &bufA[(kb + i) * RS];
      float4 x0 = *(const float4*)xr;
      float4 x1 = *(const float4*)(xr + 4);
#pragma unroll
      for (int m = 0; m < 4; ++m) {
        float wv = wA[i][m];
        acc[m][0] += wv * x0.x; acc[m][1] += wv * x0.y;
        acc[m][2] += wv * x0.z; acc[m][3] += wv * x0.w;
        acc[m][4] += wv * x1.x; acc[m][5] += wv * x1.y;
        acc[m][6] += wv * x1.z; acc[m][7] += wv * x1.w;
      }
    }

    // ---- reduce A ----
#pragma unroll
    for (int m = 0; m < 4; ++m)
#pragma unroll
      for (int b = 0; b < 8; ++b) {
        acc[m][b] += __shfl_xor(acc[m][b], 8);
        acc[m][b] += __shfl_xor(acc[m][b], 16);
        acc[m][b] += __shfl_xor(acc[m][b], 32);
      }
    if (g == 0) {
#pragma unroll
      for (int m = 0; m < 4; ++m) {
        float* p = &pA[(w * 32 + 4 * cq + m) * RS];
        *(float4*)p = make_float4(acc[m][0], acc[m][1], acc[m][2], acc[m][3]);
        *(float4*)(p + 4) = make_float4(acc[m][4], acc[m][5], acc[m][6], acc[m][7]);
      }
    }
    __syncthreads();

    // ---- finalize A: sigmoid; publish f*x (plain coalesced store) ----
    {
      float s = pA[(0 * 32 + fc) * RS + fb] + pA[(1 * 32 + fc) * RS + fb] +
                pA[(2 * 32 + fc) * RS + fb] + pA[(3 * 32 + fc) * RS + fb] + biasA;
      float sig = 1.0f / (1.0f + __expf(-s));
      if (fc < 16) {
        float xo = bufA[(64 + 16 * cg + fc) * RS + fb];
        xfg[(size_t)(bg * H_ + 16 * cg + fc) * 8 + fb] = sig * xo;
      } else {
        zreg = sig;
        xoldz = bufA[(64 + 16 * cg + (fc - 16)) * RS + fb];
      }
    }

    gbar_arrive(flags, slotA, (unsigned)(t + 1));

    // ---- y_t = x_t @ wout[cg]: overlapped with barrier-1 poll latency ----
    {
      float yp = 0.0f;
#pragma unroll
      for (int i = 0; i < 16; ++i)
        yp += wy[i] * bufA[(64 + yq + 32 * i) * RS + yb];
      yp += __shfl_xor(yp, 1);  yp += __shfl_xor(yp, 2);
      yp += __shfl_xor(yp, 4);  yp += __shfl_xor(yp, 8);
      yp += __shfl_xor(yp, 16);
      if (yq == 0)
        out[((size_t)(bg * 8 + yb) * T_ + t) * OUT_ + cg] = yp + by;
    }

    if (!gbar_wait(flags, baseA, (unsigned)(t + 1), abort_w)) return;

    // ---- stage f*x into bufA (plain dwordx4) ----
    {
      const float* src = &xfg[(size_t)(bg * H_ + tid) * 8];
      float4 p0 = *(const float4*)src;
      float4 p1 = *(const float4*)(src + 4);
      *(float4*)&bufA[(64 + tid) * RS] = p0;
      *(float4*)&bufA[(64 + tid) * RS + 4] = p1;
      src = &xfg[(size_t)(bg * H_ + tid + 256) * 8];
      p0 = *(const float4*)src;
      p1 = *(const float4*)(src + 4);
      *(float4*)&bufA[(64 + tid + 256) * RS] = p0;
      *(float4*)&bufA[(64 + tid + 256) * RS + 4] = p1;
    }
    __syncthreads();

    // ---- phase B core: r partials for 2 cols x 8 batches ----
    float acc2[2][8] = {};
#pragma unroll
    for (int i = 0; i < KSL; ++i) {
      const float* xr = &bufA[(kb + i) * RS];
      float4 x0 = *(const float4*)xr;
      float4 x1 = *(const float4*)(xr + 4);
#pragma unroll
      for (int m = 0; m < 2; ++m) {
        float wv = wB[i][m];
        acc2[m][0] += wv * x0.x; acc2[m][1] += wv * x0.y;
        acc2[m][2] += wv * x0.z; acc2[m][3] += wv * x0.w;
        acc2[m][4] += wv * x1.x; acc2[m][5] += wv * x1.y;
        acc2[m][6] += wv * x1.z; acc2[m][7] += wv * x1.w;
      }
    }
#pragma unroll
    for (int m = 0; m < 2; ++m)
#pragma unroll
      for (int b = 0; b < 8; ++b) {
        acc2[m][b] += __shfl_xor(acc2[m][b], 8);
        acc2[m][b] += __shfl_xor(acc2[m][b], 16);
        acc2[m][b] += __shfl_xor(acc2[m][b], 32);
      }
    if (g == 0) {
#pragma unroll
      for (int m = 0; m < 2; ++m) {
        float* p = &pB[(w * 16 + 2 * cq + m) * RS];
        *(float4*)p = make_float4(acc2[m][0], acc2[m][1], acc2[m][2], acc2[m][3]);
        *(float4*)(p + 4) = make_float4(acc2[m][4], acc2[m][5], acc2[m][6], acc2[m][7]);
      }
    }
    __syncthreads();

    // ---- finalize B: tanh -> rbuf ----
    if (tid < 128) {
      float s = pB[(0 * 16 + fc) * RS + fb] + pB[(1 * 16 + fc) * RS + fb] +
                pB[(2 * 16 + fc) * RS + fb] + pB[(3 * 16 + fc) * RS + fb] + biasB;
      float e = __expf(2.0f * s);
      rbuf[fc * 8 + fb] = 1.0f - 2.0f / (1.0f + e);
    }
    __syncthreads();

    // ---- update: x_next = x + z*(r - x) (plain coalesced store) ----
    if (tid >= 128) {
      float r = rbuf[(fc - 16) * 8 + fb];
      float xn = xoldz + zreg * (r - xoldz);
      xnxt[(size_t)(bg * H_ + 16 * cg + (fc - 16)) * 8 + fb] = xn;
    }

    gbar_arrive(flags, slotB, (unsigned)(t + 1));

    // ---- prefetch u_{t+1} into LDS while barrier-2 resolves ----
    if (t + 1 < T_) {
      int k2 = tid & 31, b = tid >> 5;
      float2 uv = *(const float2*)&u[((size_t)(bg * 8 + b) * T_ + (t + 1)) * IN_ + 2 * k2];
      bufA[(2 * k2) * RS + b] = uv.x;
      bufA[(2 * k2 + 1) * RS + b] = uv.y;
    }

    if (!gbar_wait(flags, baseB, (unsigned)(t + 1), abort_w)) return;
  }
}

extern "C" void kernel_launch(void* const* d_in, const int* in_sizes, int n_in,
                              void* d_out, int out_size, void* d_ws, size_t ws_size,
                              hipStream_t stream) {
  const float* u    = (const float*)d_in[0];
  const float* x0   = (const float*)d_in[1];
  const float* kfz  = (const float*)d_in[2];
  const float* bfz  = (const float*)d_in[3];
  const float* kr   = (const float*)d_in[4];
  const float* br   = (const float*)d_in[5];
  const float* wout = (const float*)d_in[6];
  const float* bout = (const float*)d_in[7];
  float* out = (float*)d_out;
  float* ws  = (float*)d_ws;

  hipLaunchKernelGGL(gru_init, dim3(64), dim3(256), 0, stream, ws, x0);
  hipLaunchKernelGGL(gru_main, dim3(NBG * NCG), dim3(NTHR), 0, stream,
                     u, kfz, bfz, kr, br, wout, bout, out, ws);
}

// Round 7
// 30803.101 us; speedup vs baseline: 1.6951x; 1.6951x over previous
//
#include <hip/hip_runtime.h>
#include <stdint.h>

// Problem dims
#define B_    64
#define T_    2048
#define IN_   64
#define H_    512
#define H2_   1024
#define OUT_  32
#define KTOT  576          // IN_ + H_

// Grid: 256 blocks = 8 batch-groups x 32 col-groups, 256 threads.
// bg = blockIdx & 7 == blockIdx % 8 -> aligns each bg's 32 blocks to one XCD
// under round-robin dispatch (perf heuristic only; correctness is placement-
// independent since all exchange goes through MALL-scope ops).
#define NBG   8
#define NCG   32
#define NTHR  256
#define BPG   8            // batches per group
#define KSL   18           // k per slice (32 slices x 18 = 576)
#define RS    12           // bufA row stride in floats

// ws layout (32-bit words)
// Flag-vector barrier: slot(bg,ph,cg) on its own 64B line. Value = t+1
// (monotone -> one-shot, no reset). NO atomics, NO data fences:
//  - data stores are agent-scope write-through (never dirty in L2)
//  - __syncthreads drains vmcnt of every wave before the flag publish
//  - flag publish is a release store by thread 0 (wbl2 on a clean L2 = cheap)
//  - consumers poll 32 distinct lines in parallel, then read data with
//    agent-scope loads (always MALL-fresh) -> no acquire-inv needed.
#define FLAG_STRIDE 16
#define FLAG_WORDS  (NBG * 2 * NCG * FLAG_STRIDE)   // 8192
#define ABORT_IDX   FLAG_WORDS                       // 8192
#define BUF_BASE    (FLAG_WORDS + 16)                // 8208, 64B-aligned
#define XSLAB       32768    // words per slab: [8 bg][512 j][8 b]

// Agent-scope relaxed ops: routed past L1/L2 to MALL; cross-XCD coherent
// with no cache-maintenance instructions.
__device__ __forceinline__ float gload(const float* p) {
  return __hip_atomic_load(p, __ATOMIC_RELAXED, __HIP_MEMORY_SCOPE_AGENT);
}
__device__ __forceinline__ void gstore(float* p, float v) {
  __hip_atomic_store(p, v, __ATOMIC_RELAXED, __HIP_MEMORY_SCOPE_AGENT);
}

__global__ __launch_bounds__(256) void gru_init(float* ws, const float* __restrict__ x0) {
  int i = blockIdx.x * blockDim.x + threadIdx.x;
  int stride = gridDim.x * blockDim.x;
  unsigned* w = (unsigned*)ws;
  for (int k = i; k < BUF_BASE; k += stride) w[k] = 0u;
  // xg0[bg][j][b] = x0[(bg*8+b)*512 + j]
  for (int k = i; k < NBG * H_ * BPG; k += stride) {
    int bg = k >> 12, j = (k >> 3) & (H_ - 1), b = k & 7;
    ws[BUF_BASE + k] = x0[(bg * 8 + b) * H_ + j];
  }
}

__device__ __forceinline__ void gbar_arrive(unsigned* flags, int slot, unsigned target) {
  __syncthreads();   // every wave: s_waitcnt vmcnt(0) -> all agent stores MALL-visible
  if (threadIdx.x == 0)
    __hip_atomic_store(flags + slot, target, __ATOMIC_RELEASE, __HIP_MEMORY_SCOPE_AGENT);
}

__device__ __forceinline__ bool gbar_wait(unsigned* flags, int base, unsigned target,
                                          unsigned* abort_w) {
  __shared__ int s_ok;
  const int tid = threadIdx.x;
  int ok = 1;
  if (tid < NCG) {   // 32 lanes of wave 0, each polls a DISTINCT 64B line
    const unsigned* f = flags + base + tid * FLAG_STRIDE;
    int polls = 0;
    while (__hip_atomic_load(f, __ATOMIC_RELAXED, __HIP_MEMORY_SCOPE_AGENT) < target) {
      __builtin_amdgcn_s_sleep(1);
      if ((++polls & 255) == 0) {
        if (__hip_atomic_load(abort_w, __ATOMIC_RELAXED, __HIP_MEMORY_SCOPE_AGENT) != 0u ||
            polls > 2000000) {
          __hip_atomic_store(abort_w, 1u, __ATOMIC_RELAXED, __HIP_MEMORY_SCOPE_AGENT);
          ok = 0;
          break;
        }
      }
    }
  }
  if (tid < 64) {
    unsigned long long bad = __ballot(ok == 0);
    if (tid == 0) s_ok = (bad == 0ull) ? 1 : 0;
  }
  __syncthreads();
  __atomic_signal_fence(__ATOMIC_ACQUIRE);  // compiler reordering guard only
  return s_ok != 0;
}

__global__ __launch_bounds__(NTHR, 1) void gru_main(
    const float* __restrict__ u, const float* __restrict__ kfz,
    const float* __restrict__ bfz, const float* __restrict__ kr,
    const float* __restrict__ br, const float* __restrict__ wout,
    const float* __restrict__ bout, float* __restrict__ out, float* ws) {
  unsigned* flags = (unsigned*)ws;
  unsigned* abort_w = flags + ABORT_IDX;
  float* xg0 = ws + BUF_BASE;
  float* xg1 = xg0 + XSLAB;
  float* xfg = xg1 + XSLAB;

  const int bg  = blockIdx.x & 7;
  const int cg  = blockIdx.x >> 3;   // column group 0..31
  const int tid = threadIdx.x;
  const int w   = tid >> 6;          // wave 0..3
  const int l   = tid & 63;
  const int cq  = l & 7;             // col-quad 0..7
  const int g   = l >> 3;            // in-wave k-slice 0..7
  const int kb  = (w * 8 + g) * KSL; // this thread's k base (18 k's)
  const int fc  = tid >> 3;          // finalize col 0..31
  const int fb  = tid & 7;           // finalize batch 0..7
  const int yb  = tid >> 5;          // y batch 0..7
  const int yq  = tid & 31;          // y k-slice 0..31

  const int slotA = ((bg * 2 + 0) * NCG + cg) * FLAG_STRIDE;
  const int slotB = ((bg * 2 + 1) * NCG + cg) * FLAG_STRIDE;
  const int baseA = (bg * 2 + 0) * NCG * FLAG_STRIDE;
  const int baseB = (bg * 2 + 1) * NCG * FLAG_STRIDE;

  __shared__ float bufA[KTOT * RS];  // [k][12]: u_t(k<64) | x or f*x
  __shared__ float pA[4 * 32 * RS];
  __shared__ float pB[4 * 16 * RS];
  __shared__ float rbuf[16 * 8];

  // ---- one-time: weights into registers ----
  float wA[KSL][4];
#pragma unroll
  for (int i = 0; i < KSL; ++i)
#pragma unroll
    for (int m = 0; m < 4; ++m) {
      int c = 4 * cq + m;
      int gcol = (c < 16) ? (16 * cg + c) : (512 + 16 * cg + (c - 16));
      wA[i][m] = kfz[(size_t)(kb + i) * H2_ + gcol];
    }
  float wB[KSL][2];
#pragma unroll
  for (int i = 0; i < KSL; ++i)
#pragma unroll
    for (int m = 0; m < 2; ++m)
      wB[i][m] = kr[(size_t)(kb + i) * H_ + (16 * cg + 2 * cq + m)];
  float wy[16];
#pragma unroll
  for (int i = 0; i < 16; ++i) wy[i] = wout[cg * H_ + (yq + 32 * i)];
  const float by = bout[cg];
  const int fzc = (fc < 16) ? (16 * cg + fc) : (512 + 16 * cg + (fc - 16));
  const float biasA = bfz[fzc];
  const float biasB = (tid < 128) ? br[16 * cg + fc] : 0.0f;

  float zreg = 0.0f, xoldz = 0.0f;

  // u_t=0 into LDS (later steps prefetched during barrier-2 window)
  {
    int k2 = tid & 31, b = tid >> 5;
    float2 uv = *(const float2*)&u[((size_t)(bg * 8 + b) * T_) * IN_ + 2 * k2];
    bufA[(2 * k2) * RS + b] = uv.x;
    bufA[(2 * k2 + 1) * RS + b] = uv.y;
  }

  for (int t = 0; t < T_; ++t) {
    float* xcur = (t & 1) ? xg1 : xg0;
    float* xnxt = (t & 1) ? xg0 : xg1;

    // ---- stage x into bufA (agent-scope loads: always MALL-fresh) ----
#pragma unroll
    for (int q = 0; q < 8; ++q) {
      bufA[(64 + tid) * RS + q]       = gload(&xcur[(size_t)(bg * H_ + tid) * 8 + q]);
      bufA[(64 + tid + 256) * RS + q] = gload(&xcur[(size_t)(bg * H_ + tid + 256) * 8 + q]);
    }
    __syncthreads();

    // ---- phase A core: fz partials for 4 cols x 8 batches over 18 k ----
    float acc[4][8] = {};
#pragma unroll
    for (int i = 0; i < KSL; ++i) {
      const float* xr = &bufA[(kb + i) * RS];
      float4 x0 = *(const float4*)xr;
      float4 x1 = *(const float4*)(xr + 4);
#pragma unroll
      for (int m = 0; m < 4; ++m) {
        float wv = wA[i][m];
        acc[m][0] += wv * x0.x; acc[m][1] += wv * x0.y;
        acc[m][2] += wv * x0.z; acc[m][3] += wv * x0.w;
        acc[m][4] += wv * x1.x; acc[m][5] += wv * x1.y;
        acc[m][6] += wv * x1.z; acc[m][7] += wv * x1.w;
      }
    }

    // ---- reduce A ----
#pragma unroll
    for (int m = 0; m < 4; ++m)
#pragma unroll
      for (int b = 0; b < 8; ++b) {
        acc[m][b] += __shfl_xor(acc[m][b], 8);
        acc[m][b] += __shfl_xor(acc[m][b], 16);
        acc[m][b] += __shfl_xor(acc[m][b], 32);
      }
    if (g == 0) {
#pragma unroll
      for (int m = 0; m < 4; ++m) {
        float* p = &pA[(w * 32 + 4 * cq + m) * RS];
        *(float4*)p = make_float4(acc[m][0], acc[m][1], acc[m][2], acc[m][3]);
        *(float4*)(p + 4) = make_float4(acc[m][4], acc[m][5], acc[m][6], acc[m][7]);
      }
    }
    __syncthreads();

    // ---- finalize A: sigmoid; publish f*x (agent store); stash z ----
    {
      float s = pA[(0 * 32 + fc) * RS + fb] + pA[(1 * 32 + fc) * RS + fb] +
                pA[(2 * 32 + fc) * RS + fb] + pA[(3 * 32 + fc) * RS + fb] + biasA;
      float sig = 1.0f / (1.0f + __expf(-s));
      if (fc < 16) {
        float xo = bufA[(64 + 16 * cg + fc) * RS + fb];
        gstore(&xfg[(size_t)(bg * H_ + 16 * cg + fc) * 8 + fb], sig * xo);
      } else {
        zreg = sig;
        xoldz = bufA[(64 + 16 * cg + (fc - 16)) * RS + fb];
      }
    }

    gbar_arrive(flags, slotA, (unsigned)(t + 1));

    // ---- y_t = x_t @ wout[cg]: overlapped with barrier-1 poll latency ----
    {
      float yp = 0.0f;
#pragma unroll
      for (int i = 0; i < 16; ++i)
        yp += wy[i] * bufA[(64 + yq + 32 * i) * RS + yb];
      yp += __shfl_xor(yp, 1);  yp += __shfl_xor(yp, 2);
      yp += __shfl_xor(yp, 4);  yp += __shfl_xor(yp, 8);
      yp += __shfl_xor(yp, 16);
      if (yq == 0)
        out[((size_t)(bg * 8 + yb) * T_ + t) * OUT_ + cg] = yp + by;
    }

    if (!gbar_wait(flags, baseA, (unsigned)(t + 1), abort_w)) return;

    // ---- stage f*x into bufA (agent-scope loads) ----
#pragma unroll
    for (int q = 0; q < 8; ++q) {
      bufA[(64 + tid) * RS + q]       = gload(&xfg[(size_t)(bg * H_ + tid) * 8 + q]);
      bufA[(64 + tid + 256) * RS + q] = gload(&xfg[(size_t)(bg * H_ + tid + 256) * 8 + q]);
    }
    __syncthreads();

    // ---- phase B core: r partials for 2 cols x 8 batches ----
    float acc2[2][8] = {};
#pragma unroll
    for (int i = 0; i < KSL; ++i) {
      const float* xr = &bufA[(kb + i) * RS];
      float4 x0 = *(const float4*)xr;
      float4 x1 = *(const float4*)(xr + 4);
#pragma unroll
      for (int m = 0; m < 2; ++m) {
        float wv = wB[i][m];
        acc2[m][0] += wv * x0.x; acc2[m][1] += wv * x0.y;
        acc2[m][2] += wv * x0.z; acc2[m][3] += wv * x0.w;
        acc2[m][4] += wv * x1.x; acc2[m][5] += wv * x1.y;
        acc2[m][6] += wv * x1.z; acc2[m][7] += wv * x1.w;
      }
    }
#pragma unroll
    for (int m = 0; m < 2; ++m)
#pragma unroll
      for (int b = 0; b < 8; ++b) {
        acc2[m][b] += __shfl_xor(acc2[m][b], 8);
        acc2[m][b] += __shfl_xor(acc2[m][b], 16);
        acc2[m][b] += __shfl_xor(acc2[m][b], 32);
      }
    if (g == 0) {
#pragma unroll
      for (int m = 0; m < 2; ++m) {
        float* p = &pB[(w * 16 + 2 * cq + m) * RS];
        *(float4*)p = make_float4(acc2[m][0], acc2[m][1], acc2[m][2], acc2[m][3]);
        *(float4*)(p + 4) = make_float4(acc2[m][4], acc2[m][5], acc2[m][6], acc2[m][7]);
      }
    }
    __syncthreads();

    // ---- finalize B: tanh -> rbuf ----
    if (tid < 128) {
      float s = pB[(0 * 16 + fc) * RS + fb] + pB[(1 * 16 + fc) * RS + fb] +
                pB[(2 * 16 + fc) * RS + fb] + pB[(3 * 16 + fc) * RS + fb] + biasB;
      float e = __expf(2.0f * s);
      rbuf[fc * 8 + fb] = 1.0f - 2.0f / (1.0f + e);
    }
    __syncthreads();

    // ---- update: x_next = x + z*(r - x) (agent store) ----
    if (tid >= 128) {
      float r = rbuf[(fc - 16) * 8 + fb];
      float xn = xoldz + zreg * (r - xoldz);
      gstore(&xnxt[(size_t)(bg * H_ + 16 * cg + (fc - 16)) * 8 + fb], xn);
    }

    gbar_arrive(flags, slotB, (unsigned)(t + 1));

    // ---- prefetch u_{t+1} into LDS while barrier-2 resolves ----
    if (t + 1 < T_) {
      int k2 = tid & 31, b = tid >> 5;
      float2 uv = *(const float2*)&u[((size_t)(bg * 8 + b) * T_ + (t + 1)) * IN_ + 2 * k2];
      bufA[(2 * k2) * RS + b] = uv.x;
      bufA[(2 * k2 + 1) * RS + b] = uv.y;
    }

    if (!gbar_wait(flags, baseB, (unsigned)(t + 1), abort_w)) return;
  }
}

extern "C" void kernel_launch(void* const* d_in, const int* in_sizes, int n_in,
                              void* d_out, int out_size, void* d_ws, size_t ws_size,
                              hipStream_t stream) {
  const float* u    = (const float*)d_in[0];
  const float* x0   = (const float*)d_in[1];
  const float* kfz  = (const float*)d_in[2];
  const float* bfz  = (const float*)d_in[3];
  const float* kr   = (const float*)d_in[4];
  const float* br   = (const float*)d_in[5];
  const float* wout = (const float*)d_in[6];
  const float* bout = (const float*)d_in[7];
  float* out = (float*)d_out;
  float* ws  = (float*)d_ws;

  hipLaunchKernelGGL(gru_init, dim3(64), dim3(256), 0, stream, ws, x0);
  hipLaunchKernelGGL(gru_main, dim3(NBG * NCG), dim3(NTHR), 0, stream,
                     u, kfz, bfz, kr, br, wout, bout, out, ws);
}

// Round 8
// 15314.160 us; speedup vs baseline: 3.4095x; 2.0114x over previous
//
#include <hip/hip_runtime.h>
#include <stdint.h>

// Problem dims
#define B_    64
#define T_    2048
#define IN_   64
#define H_    512
#define H2_   1024
#define OUT_  32
#define KTOT  576          // IN_ + H_

// Grid: 256 blocks = 8 batch-groups x 32 col-groups, 256 threads.
#define NBG   8
#define NCG   32
#define NTHR  256
#define BPG   8            // batches per group
#define KSL   18           // k per slice (32 slices x 18 = 576)
#define RS    12           // bufA row stride in floats

// ws layout (32-bit words)
#define FLAG_STRIDE 16
#define FLAG_WORDS  (NBG * 2 * NCG * FLAG_STRIDE)   // 8192
#define ABORT_IDX   FLAG_WORDS                       // 8192
#define BUF_BASE    (FLAG_WORDS + 16)                // 8208, 64B-aligned
#define XSLAB       32768    // words per slab: [8 bg][512 j][8 b]

// ---- MALL-resident exchange primitives ----
// Publish: atomic swap (no sc0 -> no return) with sc1 -> executed AT the MALL
// (agent coherence point); line stays MALL-dirty, NOT written through to HBM.
// Trailing vmcnt(0) guarantees drain before the subsequent flag/barrier
// (compiler cannot track asm-issued VMEM in its own waitcnt insertion).
__device__ __forceinline__ void gpubf(float* p, float v) {
  asm volatile("global_atomic_swap %0, %1, off sc1\n\ts_waitcnt vmcnt(0)"
               :: "v"(p), "v"(v) : "memory");
}
__device__ __forceinline__ void gpubu(unsigned* p, unsigned v) {
  asm volatile("global_atomic_swap %0, %1, off sc1\n\ts_waitcnt vmcnt(0)"
               :: "v"(p), "v"(v) : "memory");
}
// Consume: MALL-coherent 16B loads (sc0 sc1 bypass stale L1/L2), 4 in flight,
// one wait -> one latency exposure for the whole 32B-per-region stage.
__device__ __forceinline__ void gload4x4(const float* p0, const float* p1,
                                         const float* p2, const float* p3,
                                         float4& a, float4& b, float4& c, float4& d) {
  asm volatile(
      "global_load_dwordx4 %0, %4, off sc0 sc1\n\t"
      "global_load_dwordx4 %1, %5, off sc0 sc1\n\t"
      "global_load_dwordx4 %2, %6, off sc0 sc1\n\t"
      "global_load_dwordx4 %3, %7, off sc0 sc1\n\t"
      "s_waitcnt vmcnt(0)"
      : "=&v"(a), "=&v"(b), "=&v"(c), "=&v"(d)
      : "v"(p0), "v"(p1), "v"(p2), "v"(p3)
      : "memory");
}

__global__ __launch_bounds__(256) void gru_init(float* ws, const float* __restrict__ x0) {
  int i = blockIdx.x * blockDim.x + threadIdx.x;
  int stride = gridDim.x * blockDim.x;
  unsigned* w = (unsigned*)ws;
  for (int k = i; k < BUF_BASE; k += stride) w[k] = 0u;
  // xg0[bg][j][b] = x0[(bg*8+b)*512 + j]
  for (int k = i; k < NBG * H_ * BPG; k += stride) {
    int bg = k >> 12, j = (k >> 3) & (H_ - 1), b = k & 7;
    ws[BUF_BASE + k] = x0[(bg * 8 + b) * H_ + j];
  }
}

__device__ __forceinline__ void gbar_arrive(unsigned* flags, int slot, unsigned target) {
  __syncthreads();   // all publishes in this block already drained (gpubf waits)
  if (threadIdx.x == 0) gpubu(flags + slot, target);
}

__device__ __forceinline__ bool gbar_wait(unsigned* flags, int base, unsigned target,
                                          unsigned* abort_w) {
  __shared__ int s_ok;
  const int tid = threadIdx.x;
  int ok = 1;
  if (tid < NCG) {   // 32 lanes of wave 0, each polls a DISTINCT 64B line
    const unsigned* f = flags + base + tid * FLAG_STRIDE;
    int polls = 0;
    while (__hip_atomic_load(f, __ATOMIC_RELAXED, __HIP_MEMORY_SCOPE_AGENT) < target) {
      __builtin_amdgcn_s_sleep(1);
      if ((++polls & 255) == 0) {
        if (__hip_atomic_load(abort_w, __ATOMIC_RELAXED, __HIP_MEMORY_SCOPE_AGENT) != 0u ||
            polls > 2000000) {
          __hip_atomic_store(abort_w, 1u, __ATOMIC_RELAXED, __HIP_MEMORY_SCOPE_AGENT);
          ok = 0;
          break;
        }
      }
    }
  }
  if (tid < 64) {
    unsigned long long bad = __ballot(ok == 0);
    if (tid == 0) s_ok = (bad == 0ull) ? 1 : 0;
  }
  __syncthreads();
  __atomic_signal_fence(__ATOMIC_ACQUIRE);  // compiler reordering guard only
  return s_ok != 0;
}

__global__ __launch_bounds__(NTHR, 1) void gru_main(
    const float* __restrict__ u, const float* __restrict__ kfz,
    const float* __restrict__ bfz, const float* __restrict__ kr,
    const float* __restrict__ br, const float* __restrict__ wout,
    const float* __restrict__ bout, float* __restrict__ out, float* ws) {
  unsigned* flags = (unsigned*)ws;
  unsigned* abort_w = flags + ABORT_IDX;
  float* xg0 = ws + BUF_BASE;
  float* xg1 = xg0 + XSLAB;
  float* xfg = xg1 + XSLAB;

  const int bg  = blockIdx.x & 7;
  const int cg  = blockIdx.x >> 3;   // column group 0..31
  const int tid = threadIdx.x;
  const int w   = tid >> 6;          // wave 0..3
  const int l   = tid & 63;
  const int cq  = l & 7;             // col-quad 0..7
  const int g   = l >> 3;            // in-wave k-slice 0..7
  const int kb  = (w * 8 + g) * KSL; // this thread's k base (18 k's)
  const int fc  = tid >> 3;          // finalize col 0..31
  const int fb  = tid & 7;           // finalize batch 0..7
  const int yb  = tid >> 5;          // y batch 0..7
  const int yq  = tid & 31;          // y k-slice 0..31

  const int slotA = ((bg * 2 + 0) * NCG + cg) * FLAG_STRIDE;
  const int slotB = ((bg * 2 + 1) * NCG + cg) * FLAG_STRIDE;
  const int baseA = (bg * 2 + 0) * NCG * FLAG_STRIDE;
  const int baseB = (bg * 2 + 1) * NCG * FLAG_STRIDE;

  __shared__ float bufA[KTOT * RS];  // [k][12]: u_t(k<64) | x or f*x
  __shared__ float pA[4 * 32 * RS];
  __shared__ float pB[4 * 16 * RS];
  __shared__ float rbuf[16 * 8];

  // ---- one-time: weights into registers ----
  float wA[KSL][4];
#pragma unroll
  for (int i = 0; i < KSL; ++i)
#pragma unroll
    for (int m = 0; m < 4; ++m) {
      int c = 4 * cq + m;
      int gcol = (c < 16) ? (16 * cg + c) : (512 + 16 * cg + (c - 16));
      wA[i][m] = kfz[(size_t)(kb + i) * H2_ + gcol];
    }
  float wB[KSL][2];
#pragma unroll
  for (int i = 0; i < KSL; ++i)
#pragma unroll
    for (int m = 0; m < 2; ++m)
      wB[i][m] = kr[(size_t)(kb + i) * H_ + (16 * cg + 2 * cq + m)];
  float wy[16];
#pragma unroll
  for (int i = 0; i < 16; ++i) wy[i] = wout[cg * H_ + (yq + 32 * i)];
  const float by = bout[cg];
  const int fzc = (fc < 16) ? (16 * cg + fc) : (512 + 16 * cg + (fc - 16));
  const float biasA = bfz[fzc];
  const float biasB = (tid < 128) ? br[16 * cg + fc] : 0.0f;

  float zreg = 0.0f, xoldz = 0.0f;

  // u_t=0 into LDS (later steps prefetched during barrier-2 window)
  {
    int k2 = tid & 31, b = tid >> 5;
    float2 uv = *(const float2*)&u[((size_t)(bg * 8 + b) * T_) * IN_ + 2 * k2];
    bufA[(2 * k2) * RS + b] = uv.x;
    bufA[(2 * k2 + 1) * RS + b] = uv.y;
  }

  for (int t = 0; t < T_; ++t) {
    float* xcur = (t & 1) ? xg1 : xg0;
    float* xnxt = (t & 1) ? xg0 : xg1;

    // ---- stage x into bufA (MALL-coherent dwordx4; b128 LDS writes) ----
    {
      const float* s0 = &xcur[(size_t)(bg * H_ + tid) * 8];
      const float* s2 = &xcur[(size_t)(bg * H_ + tid + 256) * 8];
      float4 a, b, c, d;
      gload4x4(s0, s0 + 4, s2, s2 + 4, a, b, c, d);
      *(float4*)&bufA[(64 + tid) * RS] = a;
      *(float4*)&bufA[(64 + tid) * RS + 4] = b;
      *(float4*)&bufA[(64 + tid + 256) * RS] = c;
      *(float4*)&bufA[(64 + tid + 256) * RS + 4] = d;
    }
    __syncthreads();

    // ---- phase A core: fz partials for 4 cols x 8 batches over 18 k ----
    float acc[4][8] = {};
#pragma unroll
    for (int i = 0; i < KSL; ++i) {
      const float* xr = &bufA[(kb + i) * RS];
      float4 x0 = *(const float4*)xr;
      float4 x1 = *(const float4*)(xr + 4);
#pragma unroll
      for (int m = 0; m < 4; ++m) {
        float wv = wA[i][m];
        acc[m][0] += wv * x0.x; acc[m][1] += wv * x0.y;
        acc[m][2] += wv * x0.z; acc[m][3] += wv * x0.w;
        acc[m][4] += wv * x1.x; acc[m][5] += wv * x1.y;
        acc[m][6] += wv * x1.z; acc[m][7] += wv * x1.w;
      }
    }

    // ---- reduce A ----
#pragma unroll
    for (int m = 0; m < 4; ++m)
#pragma unroll
      for (int b = 0; b < 8; ++b) {
        acc[m][b] += __shfl_xor(acc[m][b], 8);
        acc[m][b] += __shfl_xor(acc[m][b], 16);
        acc[m][b] += __shfl_xor(acc[m][b], 32);
      }
    if (g == 0) {
#pragma unroll
      for (int m = 0; m < 4; ++m) {
        float* p = &pA[(w * 32 + 4 * cq + m) * RS];
        *(float4*)p = make_float4(acc[m][0], acc[m][1], acc[m][2], acc[m][3]);
        *(float4*)(p + 4) = make_float4(acc[m][4], acc[m][5], acc[m][6], acc[m][7]);
      }
    }
    __syncthreads();

    // ---- finalize A: sigmoid; publish f*x (MALL atomic swap); stash z ----
    {
      float s = pA[(0 * 32 + fc) * RS + fb] + pA[(1 * 32 + fc) * RS + fb] +
                pA[(2 * 32 + fc) * RS + fb] + pA[(3 * 32 + fc) * RS + fb] + biasA;
      float sig = 1.0f / (1.0f + __expf(-s));
      if (fc < 16) {
        float xo = bufA[(64 + 16 * cg + fc) * RS + fb];
        gpubf(&xfg[(size_t)(bg * H_ + 16 * cg + fc) * 8 + fb], sig * xo);
      } else {
        zreg = sig;
        xoldz = bufA[(64 + 16 * cg + (fc - 16)) * RS + fb];
      }
    }

    gbar_arrive(flags, slotA, (unsigned)(t + 1));

    // ---- y_t = x_t @ wout[cg]: overlapped with barrier-1 poll latency ----
    {
      float yp = 0.0f;
#pragma unroll
      for (int i = 0; i < 16; ++i)
        yp += wy[i] * bufA[(64 + yq + 32 * i) * RS + yb];
      yp += __shfl_xor(yp, 1);  yp += __shfl_xor(yp, 2);
      yp += __shfl_xor(yp, 4);  yp += __shfl_xor(yp, 8);
      yp += __shfl_xor(yp, 16);
      if (yq == 0)
        out[((size_t)(bg * 8 + yb) * T_ + t) * OUT_ + cg] = yp + by;
    }

    if (!gbar_wait(flags, baseA, (unsigned)(t + 1), abort_w)) return;

    // ---- stage f*x into bufA (MALL-coherent dwordx4) ----
    {
      const float* s0 = &xfg[(size_t)(bg * H_ + tid) * 8];
      const float* s2 = &xfg[(size_t)(bg * H_ + tid + 256) * 8];
      float4 a, b, c, d;
      gload4x4(s0, s0 + 4, s2, s2 + 4, a, b, c, d);
      *(float4*)&bufA[(64 + tid) * RS] = a;
      *(float4*)&bufA[(64 + tid) * RS + 4] = b;
      *(float4*)&bufA[(64 + tid + 256) * RS] = c;
      *(float4*)&bufA[(64 + tid + 256) * RS + 4] = d;
    }
    __syncthreads();

    // ---- phase B core: r partials for 2 cols x 8 batches ----
    float acc2[2][8] = {};
#pragma unroll
    for (int i = 0; i < KSL; ++i) {
      const float* xr = &bufA[(kb + i) * RS];
      float4 x0 = *(const float4*)xr;
      float4 x1 = *(const float4*)(xr + 4);
#pragma unroll
      for (int m = 0; m < 2; ++m) {
        float wv = wB[i][m];
        acc2[m][0] += wv * x0.x; acc2[m][1] += wv * x0.y;
        acc2[m][2] += wv * x0.z; acc2[m][3] += wv * x0.w;
        acc2[m][4] += wv * x1.x; acc2[m][5] += wv * x1.y;
        acc2[m][6] += wv * x1.z; acc2[m][7] += wv * x1.w;
      }
    }
#pragma unroll
    for (int m = 0; m < 2; ++m)
#pragma unroll
      for (int b = 0; b < 8; ++b) {
        acc2[m][b] += __shfl_xor(acc2[m][b], 8);
        acc2[m][b] += __shfl_xor(acc2[m][b], 16);
        acc2[m][b] += __shfl_xor(acc2[m][b], 32);
      }
    if (g == 0) {
#pragma unroll
      for (int m = 0; m < 2; ++m) {
        float* p = &pB[(w * 16 + 2 * cq + m) * RS];
        *(float4*)p = make_float4(acc2[m][0], acc2[m][1], acc2[m][2], acc2[m][3]);
        *(float4*)(p + 4) = make_float4(acc2[m][4], acc2[m][5], acc2[m][6], acc2[m][7]);
      }
    }
    __syncthreads();

    // ---- finalize B: tanh -> rbuf ----
    if (tid < 128) {
      float s = pB[(0 * 16 + fc) * RS + fb] + pB[(1 * 16 + fc) * RS + fb] +
                pB[(2 * 16 + fc) * RS + fb] + pB[(3 * 16 + fc) * RS + fb] + biasB;
      float e = __expf(2.0f * s);
      rbuf[fc * 8 + fb] = 1.0f - 2.0f / (1.0f + e);
    }
    __syncthreads();

    // ---- update: x_next = x + z*(r - x) (MALL atomic swap) ----
    if (tid >= 128) {
      float r = rbuf[(fc - 16) * 8 + fb];
      float xn = xoldz + zreg * (r - xoldz);
      gpubf(&xnxt[(size_t)(bg * H_ + 16 * cg + (fc - 16)) * 8 + fb], xn);
    }

    gbar_arrive(flags, slotB, (unsigned)(t + 1));

    // ---- prefetch u_{t+1} into LDS while barrier-2 resolves ----
    if (t + 1 < T_) {
      int k2 = tid & 31, b = tid >> 5;
      float2 uv = *(const float2*)&u[((size_t)(bg * 8 + b) * T_ + (t + 1)) * IN_ + 2 * k2];
      bufA[(2 * k2) * RS + b] = uv.x;
      bufA[(2 * k2 + 1) * RS + b] = uv.y;
    }

    if (!gbar_wait(flags, baseB, (unsigned)(t + 1), abort_w)) return;
  }
}

extern "C" void kernel_launch(void* const* d_in, const int* in_sizes, int n_in,
                              void* d_out, int out_size, void* d_ws, size_t ws_size,
                              hipStream_t stream) {
  const float* u    = (const float*)d_in[0];
  const float* x0   = (const float*)d_in[1];
  const float* kfz  = (const float*)d_in[2];
  const float* bfz  = (const float*)d_in[3];
  const float* kr   = (const float*)d_in[4];
  const float* br   = (const float*)d_in[5];
  const float* wout = (const float*)d_in[6];
  const float* bout = (const float*)d_in[7];
  float* out = (float*)d_out;
  float* ws  = (float*)d_ws;

  hipLaunchKernelGGL(gru_init, dim3(64), dim3(256), 0, stream, ws, x0);
  hipLaunchKernelGGL(gru_main, dim3(NBG * NCG), dim3(NTHR), 0, stream,
                     u, kfz, bfz, kr, br, wout, bout, out, ws);
}